// Round 6
// baseline (237.237 us; speedup 1.0000x reference)
//
#include <hip/hip_runtime.h>

// BeliefMatchingLoss: pred [8,19,512,512] f32 logits, target [8,512,512] int.
// loss = mean over valid px of COEF*KL(Dir(alpha)||Dir(1)) - (psi(a_ans)-psi(a0))
//
// Math: shift-1 recurrence, y = a+1 = exp(x)+1:
//   psi(a)    = psi(y) - 1/a
//   lnGamma(a)= lnGamma(y) - ln a = lnGamma(y) - x      <- logit IS ln a, free
// psi(y)  = ln y - r/2 - r^2/12 + r^4/120 - r^6/252      (r=1/y)
// lnG(y)  = (y-.5)ln y - y + ln(2pi)/2 + r/12 - r^3/360 + r^5/1260
// Worst-case series bias ~1.7e-3; scalar threshold 0.1 -> 50x margin.
//
// R5 lesson: a 76-VGPR register prefetch queue under a 128-VGPR cap starves
// the chan pipeline of registers (spill or low ILP) and caps occupancy at
// 4 waves/SIMD -- inferred bml_main ~77us vs ~30us model. R6: stage via
// global_load_lds (no VGPR round-trip), 19KB LDS/block -> 8 blocks/CU (full
// 32 waves/CU); the per-step vmcnt(0)+barrier drain is hidden by cross-block
// TLP. VGPR drops to ~45.

#define NCLS 19
#define HW (512 * 512)          // 2^18
#define NPIX (8 * HW)           // 2097152
#define TPB 256
#define STEPS 4
#define NBLK (NPIX / (TPB * STEPS))   // 2048
#define IGNORE_IDX 255

#define PC1 0.08333333333f      // 1/12
#define PC2 0.00833333333f      // 1/120
#define PC3 0.00396825397f      // 1/252
#define GL1 0.08333333333f      // 1/12
#define GL2 0.00277777778f      // 1/360
#define GL3 0.00079365079f      // 1/1260
#define HLN2PI 0.9189385332f    // ln(2*pi)/2
#define SUM_HLN2PI 17.45983213f // NCLS * ln(2*pi)/2

__device__ __forceinline__ float fast_rcp(float x) { return __builtin_amdgcn_rcpf(x); }

struct Acc {
    float a0, s2, slgx, dgans;   // slgx accumulates (lnG(y) - HLN2PI - x)
};

__device__ __forceinline__ void chan(float x, int c, int tc, Acc& A) {
    float a   = __expf(x);
    float y   = a + 1.f;
    float rpy = fast_rcp(a * y);
    float r   = a * rpy;                 // 1/y
    float rp  = y * rpy;                 // 1/a
    float ly  = __logf(y);
    float r2  = r * r;
    float T   = __fmaf_rn(-r2, __fmaf_rn(-r2, PC3, PC2), PC1);
    float psiy = __fmaf_rn(-r2, T, __fmaf_rn(-0.5f, r, ly));
    float psia = psiy - rp;
    A.s2 = __fmaf_rn(a - 1.f, psia, A.s2);
    A.a0 += a;
    float G   = __fmaf_rn(-r2, __fmaf_rn(-r2, GL3, GL2), GL1);
    float lgp = __fmaf_rn(y - 0.5f, ly, -y) - x;
    A.slgx = __fmaf_rn(r, G, A.slgx + lgp);
    A.dgans = (c == tc) ? psia : A.dgans;
}

__device__ __forceinline__ float finish(const Acc& A) {
    float a0  = A.a0;
    float y   = a0 + 1.f;
    float rpy = fast_rcp(a0 * y);
    float r   = a0 * rpy;                // 1/y
    float rp  = y * rpy;                 // 1/a0
    float ly  = __logf(y);
    float la  = __logf(a0);
    float r2  = r * r;
    float T   = __fmaf_rn(-r2, __fmaf_rn(-r2, PC3, PC2), PC1);
    float psi0 = __fmaf_rn(-r2, T, __fmaf_rn(-0.5f, r, ly)) - rp;
    float G   = __fmaf_rn(-r2, __fmaf_rn(-r2, GL3, GL2), GL1);
    float lg0 = __fmaf_rn(y - 0.5f, ly, -y) + HLN2PI + r * G - la;

    float sum_lg = A.slgx + SUM_HLN2PI;              // sum_c lnGamma(a_c)
    float ll    = A.dgans - psi0;
    float loss1 = lg0 - sum_lg;
    float loss2 = A.s2 - psi0 * (a0 - (float)NCLS);
    return 0.01f * (loss1 + loss2) - ll;
}

__global__ __launch_bounds__(256, 8) void bml_main(const float* __restrict__ pred,
                                                   const int* __restrict__ target,
                                                   float* __restrict__ partial) {
    __shared__ float lds[NCLS * TPB];    // 19 KB: [c][256] px-major rows

    const int base_px = blockIdx.x * (TPB * STEPS);   // 1024-px block span
    const int b   = base_px >> 18;
    const int hw0 = base_px & (HW - 1);
    const float* pbase = pred + (size_t)b * NCLS * HW + hw0;
    const int wave = threadIdx.x >> 6, lane = threadIdx.x & 63;

    float local = 0.f, cnt = 0.f;

    for (int s = 0; s < STEPS; ++s) {
        // Stage 19 channel rows (256 px x 4B = 1 KB each) via global_load_lds
        // width-16: lane l moves bytes [16l,16l+16) of the row. Wave w takes
        // channels w, w+4, ... (5,5,5,4 split).
        for (int c = wave; c < NCLS; c += 4) {
            const float* g = pbase + (size_t)c * HW + s * TPB + lane * 4;
            __builtin_amdgcn_global_load_lds(
                (const __attribute__((address_space(1))) void*)g,
                (__attribute__((address_space(3))) void*)&lds[c * TPB + lane * 4],
                16, 0, 0);
        }
        int t = target[base_px + s * TPB + threadIdx.x];

        __syncthreads();   // emits s_waitcnt vmcnt(0) lgkmcnt(0) + s_barrier

        int tc = (t == IGNORE_IDX) ? 0 : t;
        Acc A = {0.f, 0.f, 0.f, 0.f};
        #pragma unroll
        for (int c = 0; c < NCLS; ++c)
            chan(lds[c * TPB + threadIdx.x], c, tc, A);   // 2-way bank alias: free

        float l = finish(A);
        if (t != IGNORE_IDX) { local += l; cnt += 1.f; }

        __syncthreads();   // protect LDS before next step's staging
    }

    // block reduction (no atomics -- R5 lesson)
    #pragma unroll
    for (int off = 32; off; off >>= 1) {
        local += __shfl_down(local, off);
        cnt   += __shfl_down(cnt, off);
    }
    __shared__ float s_sum[4];
    __shared__ float s_cnt[4];
    if (lane == 0) { s_sum[wave] = local; s_cnt[wave] = cnt; }
    __syncthreads();
    if (threadIdx.x == 0) {
        partial[blockIdx.x]        = s_sum[0] + s_sum[1] + s_sum[2] + s_sum[3];
        partial[NBLK + blockIdx.x] = s_cnt[0] + s_cnt[1] + s_cnt[2] + s_cnt[3];
    }
}

__global__ __launch_bounds__(256) void bml_finalize(const float* __restrict__ partial,
                                                    float* __restrict__ out) {
    double s = 0.0, n = 0.0;
    for (int i = threadIdx.x; i < NBLK; i += 256) {
        s += (double)partial[i];
        n += (double)partial[NBLK + i];
    }
    #pragma unroll
    for (int off = 32; off; off >>= 1) {
        s += __shfl_down(s, off);
        n += __shfl_down(n, off);
    }
    __shared__ double sh_s[4], sh_n[4];
    int lane = threadIdx.x & 63, wid = threadIdx.x >> 6;
    if (lane == 0) { sh_s[wid] = s; sh_n[wid] = n; }
    __syncthreads();
    if (threadIdx.x == 0) {
        double ts = sh_s[0] + sh_s[1] + sh_s[2] + sh_s[3];
        double tn = sh_n[0] + sh_n[1] + sh_n[2] + sh_n[3];
        out[0] = (float)(ts / tn);
    }
}

extern "C" void kernel_launch(void* const* d_in, const int* in_sizes, int n_in,
                              void* d_out, int out_size, void* d_ws, size_t ws_size,
                              hipStream_t stream) {
    const float* pred = (const float*)d_in[0];
    const int* target = (const int*)d_in[1];
    float* out = (float*)d_out;
    float* partial = (float*)d_ws;   // 2*NBLK floats; every slot written

    bml_main<<<NBLK, TPB, 0, stream>>>(pred, target, partial);
    bml_finalize<<<1, 256, 0, stream>>>(partial, out);
}